// Round 1
// baseline (579.622 us; speedup 1.0000x reference)
//
#include <hip/hip_runtime.h>
#include <hip/hip_bf16.h>

#define T_LEN 4096
#define BATCH 8
#define D_DIM 256
#define P_DIM 256
#define O_DIM 256
#define N3    768

typedef __bf16 bf16;
typedef __attribute__((ext_vector_type(8))) __bf16 bf16x8;
typedef __attribute__((ext_vector_type(4))) __bf16 bf16x4;
typedef __attribute__((ext_vector_type(4))) float f32x4;

#define LDA 264   // 256 + 8 pad (bf16 elems): row stride 528B -> 2-way-max bank aliasing on b128
#define LDV 40    // 32 + 8 pad for Vt / Ps tiles

// ---------------------------------------------------------------------------
// K1: qkv = query @ W_kqv + b_kqv ; scatter to q(scaled,[B][T][P]), k([B][S][P]),
//     v TRANSPOSED to [B][P][S] so flash PV B-fragments are s-contiguous.
// grid (512, 12), block 256
// ---------------------------------------------------------------------------
__global__ __launch_bounds__(256) void qkv_proj_kernel(
    const float* __restrict__ query, const float* __restrict__ W_kqv,
    const float* __restrict__ b_kqv,
    bf16* __restrict__ qb, bf16* __restrict__ kb, bf16* __restrict__ vt)
{
    __shared__ __align__(16) bf16 As[64][LDA];
    __shared__ __align__(16) bf16 Bs[64][LDA];
    const int m0 = blockIdx.x * 64;
    const int n0 = blockIdx.y * 64;
    const int tid  = threadIdx.x;
    const int lane = tid & 63;
    const int wave = tid >> 6;
    const int l15  = lane & 15;
    const int quad = lane >> 4;

    // A tile: 64 rows of query (fp32 -> bf16)
    {
        const int i  = tid >> 2;
        const int c0 = (tid & 3) * 64;
        const float* src = query + (size_t)(m0 + i) * D_DIM + c0;
        for (int u = 0; u < 16; ++u) {
            float4 f = ((const float4*)src)[u];
            bf16x4 h = { (bf16)f.x, (bf16)f.y, (bf16)f.z, (bf16)f.w };
            *(bf16x4*)&As[i][c0 + u * 4] = h;
        }
    }
    // B tile: W_kqv[k][n] -> Bs[n][k] (transposed, bf16)
    {
        const int k = tid;  // 0..255
        const float* src = W_kqv + (size_t)k * N3 + n0;
        for (int u = 0; u < 16; ++u) {
            float4 f = ((const float4*)src)[u];
            Bs[u * 4 + 0][k] = (bf16)f.x;
            Bs[u * 4 + 1][k] = (bf16)f.y;
            Bs[u * 4 + 2][k] = (bf16)f.z;
            Bs[u * 4 + 3][k] = (bf16)f.w;
        }
    }
    __syncthreads();

    f32x4 acc[4];
    for (int i = 0; i < 4; ++i) acc[i] = {0.f, 0.f, 0.f, 0.f};

    const int arow = wave * 16 + l15;
    for (int kt = 0; kt < 8; ++kt) {
        bf16x8 a = *(const bf16x8*)&As[arow][kt * 32 + quad * 8];
        for (int nt = 0; nt < 4; ++nt) {
            bf16x8 bb = *(const bf16x8*)&Bs[nt * 16 + l15][kt * 32 + quad * 8];
            acc[nt] = __builtin_amdgcn_mfma_f32_16x16x32_bf16(a, bb, acc[nt], 0, 0, 0);
        }
    }

    // epilogue: C/D layout col = lane&15, row = quad*4 + reg (verified m89/m91)
    for (int nt = 0; nt < 4; ++nt) {
        const int c = n0 + nt * 16 + l15;
        const float bias = b_kqv[c];
        for (int r = 0; r < 4; ++r) {
            const int m = m0 + wave * 16 + quad * 4 + r;
            const int t = m >> 3, bi = m & 7;
            const float v = acc[nt][r] + bias;
            if (c < 256) {
                qb[((size_t)bi * T_LEN + t) * P_DIM + c] = (bf16)(v * 0.0625f);  // P^-0.5
            } else if (c < 512) {
                kb[((size_t)bi * T_LEN + t) * P_DIM + (c - 256)] = (bf16)v;
            } else {
                vt[((size_t)bi * P_DIM + (c - 512)) * T_LEN + t] = (bf16)v;      // V^T
            }
        }
    }
}

// ---------------------------------------------------------------------------
// K2: flash attention. 512 blocks (b = bid&7 for XCD/L2 locality), 4 waves,
// Q-tile 64 rows (16/wave, Q frags in regs), S-tile 32. fp32 online softmax.
// ---------------------------------------------------------------------------
__global__ __launch_bounds__(256) void flash_attn_kernel(
    const bf16* __restrict__ qb, const bf16* __restrict__ kb,
    const bf16* __restrict__ vt, bf16* __restrict__ attn)
{
    __shared__ __align__(16) bf16 Ks[32][LDA];
    __shared__ __align__(16) bf16 Vs[256][LDV];   // [p][s] tile
    __shared__ __align__(16) bf16 Ps[4][16][LDV]; // per-wave P round-trip

    const int bid = blockIdx.x;
    const int b   = bid & 7;
    const int t0  = (bid >> 3) * 64;
    const int tid  = threadIdx.x;
    const int lane = tid & 63;
    const int wave = tid >> 6;
    const int l15  = lane & 15;
    const int quad = lane >> 4;

    // Q fragments in registers: 16 rows per wave, K=256 -> 8 chunks of 32
    bf16x8 qf[8];
    {
        const bf16* qrow = qb + ((size_t)b * T_LEN + t0 + wave * 16 + l15) * P_DIM + quad * 8;
        for (int kt = 0; kt < 8; ++kt) qf[kt] = *(const bf16x8*)(qrow + kt * 32);
    }

    f32x4 acc_o[16];
    for (int i = 0; i < 16; ++i) acc_o[i] = {0.f, 0.f, 0.f, 0.f};
    float m_r[4], l_r[4];
    for (int r = 0; r < 4; ++r) { m_r[r] = -1e30f; l_r[r] = 0.f; }

    for (int s0 = 0; s0 < T_LEN; s0 += 32) {
        __syncthreads();  // prior iteration's reads of Ks/Vs complete
        // K tile: 32 rows x 256 (coalesced)
        {
            const int i  = tid >> 3;
            const int c0 = (tid & 7) * 32;
            const bf16* src = kb + ((size_t)b * T_LEN + s0 + i) * P_DIM + c0;
            for (int u = 0; u < 4; ++u)
                *(bf16x8*)&Ks[i][c0 + u * 8] = *(const bf16x8*)(src + u * 8);
        }
        // V^T tile: 256 p-rows x 32 s (rows strided in global, 64B/row touched)
        {
            const int p = tid;
            const bf16* src = vt + ((size_t)b * P_DIM + p) * T_LEN + s0;
            for (int u = 0; u < 4; ++u)
                *(bf16x8*)&Vs[p][u * 8] = *(const bf16x8*)(src + u * 8);
        }
        __syncthreads();

        // S = Q K^T (q pre-scaled). 16 rows x 32 cols per wave.
        f32x4 accs[2];
        accs[0] = {0.f, 0.f, 0.f, 0.f};
        accs[1] = {0.f, 0.f, 0.f, 0.f};
        for (int kt = 0; kt < 8; ++kt) {
            for (int nt = 0; nt < 2; ++nt) {
                bf16x8 bb = *(const bf16x8*)&Ks[nt * 16 + l15][kt * 32 + quad * 8];
                accs[nt] = __builtin_amdgcn_mfma_f32_16x16x32_bf16(qf[kt], bb, accs[nt], 0, 0, 0);
            }
        }

        // online softmax: lane owns rows quad*4+r ; cols spread over l15 (16 lanes)
        float nm[4], alpha[4];
        for (int r = 0; r < 4; ++r) {
            float mx = fmaxf(accs[0][r], accs[1][r]);
            for (int msk = 1; msk < 16; msk <<= 1) mx = fmaxf(mx, __shfl_xor(mx, msk, 64));
            nm[r]    = fmaxf(m_r[r], mx);
            alpha[r] = __expf(m_r[r] - nm[r]);
            m_r[r]   = nm[r];
        }
        float rs[4] = {0.f, 0.f, 0.f, 0.f};
        for (int nt = 0; nt < 2; ++nt)
            for (int r = 0; r < 4; ++r) {
                float p = __expf(accs[nt][r] - nm[r]);
                accs[nt][r] = p;
                rs[r] += p;
            }
        for (int r = 0; r < 4; ++r) {
            for (int msk = 1; msk < 16; msk <<= 1) rs[r] += __shfl_xor(rs[r], msk, 64);
            l_r[r] = l_r[r] * alpha[r] + rs[r];
        }
        // rescale O only when some row max moved (rare after warmup)
        bool need = (alpha[0] < 1.f) || (alpha[1] < 1.f) || (alpha[2] < 1.f) || (alpha[3] < 1.f);
        if (__any(need)) {
            for (int nt = 0; nt < 16; ++nt)
                for (int r = 0; r < 4; ++r) acc_o[nt][r] *= alpha[r];
        }

        // P -> per-wave LDS (C-layout write), reread as A-fragment. Same-wave DS
        // ops are in-order: no barrier needed.
        for (int nt = 0; nt < 2; ++nt)
            for (int r = 0; r < 4; ++r)
                Ps[wave][quad * 4 + r][nt * 16 + l15] = (bf16)accs[nt][r];
        bf16x8 ap = *(const bf16x8*)&Ps[wave][l15][quad * 8];

        // O += P @ V : B-frag from Vs[p][s] (n=p, k=s)
        for (int nt = 0; nt < 16; ++nt) {
            bf16x8 bb = *(const bf16x8*)&Vs[nt * 16 + l15][quad * 8];
            acc_o[nt] = __builtin_amdgcn_mfma_f32_16x16x32_bf16(ap, bb, acc_o[nt], 0, 0, 0);
        }
    }

    // epilogue: attn[(t*B + b)*P + p], normalized
    for (int nt = 0; nt < 16; ++nt) {
        for (int r = 0; r < 4; ++r) {
            const int t = t0 + wave * 16 + quad * 4 + r;
            const int p = nt * 16 + l15;
            attn[((size_t)t * BATCH + b) * P_DIM + p] = (bf16)(acc_o[nt][r] / l_r[r]);
        }
    }
}

// ---------------------------------------------------------------------------
// K3: out = attn @ W_out + b_out (fp32 out). grid (512, 4), block 256
// ---------------------------------------------------------------------------
__global__ __launch_bounds__(256) void out_proj_kernel(
    const bf16* __restrict__ attn, const float* __restrict__ W_out,
    const float* __restrict__ b_out, float* __restrict__ out)
{
    __shared__ __align__(16) bf16 As[64][LDA];
    __shared__ __align__(16) bf16 Bs[64][LDA];
    const int m0 = blockIdx.x * 64;
    const int n0 = blockIdx.y * 64;
    const int tid  = threadIdx.x;
    const int lane = tid & 63;
    const int wave = tid >> 6;
    const int l15  = lane & 15;
    const int quad = lane >> 4;

    {
        const int i  = tid >> 2;
        const int c0 = (tid & 3) * 64;
        const bf16* src = attn + (size_t)(m0 + i) * P_DIM + c0;
        for (int u = 0; u < 8; ++u)
            *(bf16x8*)&As[i][c0 + u * 8] = *(const bf16x8*)(src + u * 8);
    }
    {
        const int k = tid;
        const float* src = W_out + (size_t)k * O_DIM + n0;
        for (int u = 0; u < 16; ++u) {
            float4 f = ((const float4*)src)[u];
            Bs[u * 4 + 0][k] = (bf16)f.x;
            Bs[u * 4 + 1][k] = (bf16)f.y;
            Bs[u * 4 + 2][k] = (bf16)f.z;
            Bs[u * 4 + 3][k] = (bf16)f.w;
        }
    }
    __syncthreads();

    f32x4 acc[4];
    for (int i = 0; i < 4; ++i) acc[i] = {0.f, 0.f, 0.f, 0.f};

    const int arow = wave * 16 + l15;
    for (int kt = 0; kt < 8; ++kt) {
        bf16x8 a = *(const bf16x8*)&As[arow][kt * 32 + quad * 8];
        for (int nt = 0; nt < 4; ++nt) {
            bf16x8 bb = *(const bf16x8*)&Bs[nt * 16 + l15][kt * 32 + quad * 8];
            acc[nt] = __builtin_amdgcn_mfma_f32_16x16x32_bf16(a, bb, acc[nt], 0, 0, 0);
        }
    }

    for (int nt = 0; nt < 4; ++nt) {
        const int n = n0 + nt * 16 + l15;
        const float bias = b_out[n];
        for (int r = 0; r < 4; ++r) {
            const int m = m0 + wave * 16 + quad * 4 + r;
            out[(size_t)m * O_DIM + n] = acc[nt][r] + bias;
        }
    }
}

extern "C" void kernel_launch(void* const* d_in, const int* in_sizes, int n_in,
                              void* d_out, int out_size, void* d_ws, size_t ws_size,
                              hipStream_t stream) {
    const float* query = (const float*)d_in[0];
    const float* W_kqv = (const float*)d_in[1];
    const float* b_kqv = (const float*)d_in[2];
    const float* W_out = (const float*)d_in[3];
    const float* b_out = (const float*)d_in[4];
    float* out = (float*)d_out;

    const size_t BUF = (size_t)BATCH * T_LEN * P_DIM;  // 8.39M elems
    bf16* qb   = (bf16*)d_ws;
    bf16* kb   = qb + BUF;
    bf16* vt   = kb + BUF;   // [B][P][S] transposed
    bf16* attn = vt + BUF;   // [T][B][P]

    qkv_proj_kernel<<<dim3(512, 12), 256, 0, stream>>>(query, W_kqv, b_kqv, qb, kb, vt);
    flash_attn_kernel<<<512, 256, 0, stream>>>(qb, kb, vt, attn);
    out_proj_kernel<<<dim3(512, 4), 256, 0, stream>>>(attn, W_out, b_out, out);
}